// Round 1
// baseline (206.631 us; speedup 1.0000x reference)
//
#include <hip/hip_runtime.h>
#include <math.h>

// Problem constants (B, N, D2, S = 64, 4096, 128, 512)
#define BB 64
#define NN 4096
#define DD 128
#define SS 512
#define CHUNKS 16          // blocks per b
#define RPC 256            // rows per chunk = NN / CHUNKS
#define SUBT 4             // 64-row subtiles per chunk

// ---------------------------------------------------------------------------
// Fused kernel v2: direct global->register streaming (no LDS staging of
// y_past, no barriers in the stream loop). Per (b, chunk) block of 256
// threads:
//   - 4 threads per row; thread (r, j) owns the contiguous 128 B quarter
//     [j*32 .. j*32+31] of each of its 4 rows (r, r+64, r+128, r+192).
//     8 consecutive float4 loads per row-quarter; same-line requests from
//     the unrolled k-loop merge in L1/MSHR -> exact HBM traffic, 32
//     independent loads in flight per thread, zero barriers while streaming.
//   - subtile-0 first half + s_past indices prefetched BEFORE the q = yq@w
//     phase so the q dependency chain hides under the first HBM round-trip.
//   - chunk max via shuffle + tiny LDS; scatter exp(p - m_c) into LDS bins;
//     write bins + m_c to workspace (combine kernel unchanged).
// ---------------------------------------------------------------------------
__global__ __launch_bounds__(256, 4) void fused_kernel(
    const float* __restrict__ y_past, const float* __restrict__ yq,
    const float* __restrict__ w, const int* __restrict__ s_past,
    float* __restrict__ bins_g, float* __restrict__ pmax) {
    const int b = blockIdx.x, chunk = blockIdx.y;
    const int t = threadIdx.x;
    const int j = t & 3;   // quarter of row (32 floats)
    const int r = t >> 2;  // row within 64-row subtile

    __shared__ float syq[DD];
    __shared__ float qsh[DD];
    __shared__ float bins[SS];
    __shared__ float wred[8];

    const float4* gp =
        (const float4*)y_past + ((size_t)b * NN + (size_t)chunk * RPC) * 32;

    // ---- early: issue subtile-0 prefetch (k=0..3) + s_past index loads;
    //      neither depends on q, so they overlap the q-phase below.
    float4 y0[4];
#pragma unroll
    for (int k = 0; k < 4; ++k) y0[k] = gp[(size_t)r * 32 + j * 8 + k];

    int sreg[SUBT];
    if (j == 0) {
#pragma unroll
        for (int s = 0; s < SUBT; ++s)
            sreg[s] = s_past[(size_t)b * NN + chunk * RPC + s * 64 + r];
    }

    if (t < DD) syq[t] = yq[b * DD + t];
    bins[t] = 0.f;
    bins[t + 256] = 0.f;
    __syncthreads();

    // ---- q = yq @ w (threads 0..127, one output column each; w L2-resident)
    if (t < DD) {
        float acc = 0.f;
#pragma unroll
        for (int d = 0; d < DD; ++d) acc = fmaf(syq[d], w[d * DD + t], acc);
        qsh[t] = acc;
    }
    __syncthreads();

    float4 qreg[8];
#pragma unroll
    for (int k = 0; k < 8; ++k) qreg[k] = ((const float4*)qsh)[j * 8 + k];

    float pv[SUBT];

    // ---- subtile 0: first half from prefetch regs, second half fresh
    {
        float4 acc = {0.f, 0.f, 0.f, 0.f};
#pragma unroll
        for (int k = 0; k < 4; ++k) {
            acc.x = fmaf(qreg[k].x, y0[k].x, acc.x);
            acc.y = fmaf(qreg[k].y, y0[k].y, acc.y);
            acc.z = fmaf(qreg[k].z, y0[k].z, acc.z);
            acc.w = fmaf(qreg[k].w, y0[k].w, acc.w);
        }
#pragma unroll
        for (int k = 4; k < 8; ++k) {
            float4 yv = gp[(size_t)r * 32 + j * 8 + k];
            acc.x = fmaf(qreg[k].x, yv.x, acc.x);
            acc.y = fmaf(qreg[k].y, yv.y, acc.y);
            acc.z = fmaf(qreg[k].z, yv.z, acc.z);
            acc.w = fmaf(qreg[k].w, yv.w, acc.w);
        }
        float p = (acc.x + acc.y) + (acc.z + acc.w);
        p += __shfl_xor(p, 1, 64);
        p += __shfl_xor(p, 2, 64);  // all 4 lanes of row-group hold full dot
        pv[0] = p;
    }

    // ---- subtiles 1..3: straight global->reg, no barriers
#pragma unroll
    for (int s = 1; s < SUBT; ++s) {
        float4 acc = {0.f, 0.f, 0.f, 0.f};
#pragma unroll
        for (int k = 0; k < 8; ++k) {
            float4 yv = gp[(size_t)(s * 64 + r) * 32 + j * 8 + k];
            acc.x = fmaf(qreg[k].x, yv.x, acc.x);
            acc.y = fmaf(qreg[k].y, yv.y, acc.y);
            acc.z = fmaf(qreg[k].z, yv.z, acc.z);
            acc.w = fmaf(qreg[k].w, yv.w, acc.w);
        }
        float p = (acc.x + acc.y) + (acc.z + acc.w);
        p += __shfl_xor(p, 1, 64);
        p += __shfl_xor(p, 2, 64);
        pv[s] = p;
    }

    // ---- chunk max over 256 rows ----
    float m = fmaxf(fmaxf(pv[0], pv[1]), fmaxf(pv[2], pv[3]));
#pragma unroll
    for (int off = 32; off > 0; off >>= 1) m = fmaxf(m, __shfl_xor(m, off, 64));
    int wave = t >> 6, lane = t & 63;
    if (lane == 0) wred[wave] = m;
    __syncthreads();
    m = fmaxf(fmaxf(wred[0], wred[1]), fmaxf(wred[2], wred[3]));

    // ---- scatter exp(p - m_c) into LDS bins (j==0 lane of each row group)
    if (j == 0) {
#pragma unroll
        for (int s = 0; s < SUBT; ++s)
            atomicAdd(&bins[sreg[s]], __expf(pv[s] - m));
    }
    __syncthreads();

    // ---- write chunk bins + max ----
    float* bg = bins_g + ((size_t)b * CHUNKS + chunk) * SS;
    bg[t] = bins[t];
    bg[t + 256] = bins[t + 256];
    if (t == 0) pmax[b * CHUNKS + chunk] = m;
}

// ---------------------------------------------------------------------------
// Combine: out[b,s] = (sum_c bins[b,c,s] * exp(m_c - M)) / S,
// S recovered as the block-wide sum of the numerators. 64 blocks x 512 thr.
// ---------------------------------------------------------------------------
__global__ __launch_bounds__(512) void combine_kernel(
    const float* __restrict__ bins_g, const float* __restrict__ pmax,
    float* __restrict__ out) {
    int b = blockIdx.x;
    int t = threadIdx.x;  // 0..511
    __shared__ float scale[CHUNKS];
    __shared__ float red[8];
    __shared__ float sInv;

    if (t < CHUNKS) scale[t] = pmax[b * CHUNKS + t];
    __syncthreads();
    if (t == 0) {
        float M = scale[0];
#pragma unroll
        for (int c = 1; c < CHUNKS; ++c) M = fmaxf(M, scale[c]);
#pragma unroll
        for (int c = 0; c < CHUNKS; ++c) scale[c] = __expf(scale[c] - M);
    }
    __syncthreads();

    float acc = 0.f;
#pragma unroll
    for (int c = 0; c < CHUNKS; ++c)
        acc = fmaf(bins_g[((size_t)b * CHUNKS + c) * SS + t], scale[c], acc);

    float s = acc;
#pragma unroll
    for (int off = 32; off > 0; off >>= 1) s += __shfl_xor(s, off, 64);
    if ((t & 63) == 0) red[t >> 6] = s;
    __syncthreads();
    if (t == 0) {
        float S = 0.f;
#pragma unroll
        for (int i = 0; i < 8; ++i) S += red[i];
        sInv = 1.f / S;
    }
    __syncthreads();

    out[b * SS + t] = acc * sInv;
}

// ---------------------------------------------------------------------------
// Launch. Inputs: [0]=s_past(int B*N), [1]=yq(f32 B*D2), [2]=y_past(f32
// B*N*D2), [3]=w_mat(f32 D2*D2), [4]=size_s. Out: post_est f32 B*S.
// ws: bins_g (B*CHUNKS*S = 2 MB) | pmax (B*CHUNKS)
// ---------------------------------------------------------------------------
extern "C" void kernel_launch(void* const* d_in, const int* in_sizes, int n_in,
                              void* d_out, int out_size, void* d_ws, size_t ws_size,
                              hipStream_t stream) {
    const int*   s_past = (const int*)d_in[0];
    const float* yq     = (const float*)d_in[1];
    const float* y_past = (const float*)d_in[2];
    const float* w_mat  = (const float*)d_in[3];

    float* ws     = (float*)d_ws;
    float* bins_g = ws;                         // BB*CHUNKS*SS floats
    float* pmax   = bins_g + BB * CHUNKS * SS;  // BB*CHUNKS floats
    float* out    = (float*)d_out;

    fused_kernel<<<dim3(BB, CHUNKS), 256, 0, stream>>>(y_past, yq, w_mat,
                                                       s_past, bins_g, pmax);
    combine_kernel<<<BB, SS, 0, stream>>>(bins_g, pmax, out);
}